// Round 6
// baseline (492.833 us; speedup 1.0000x reference)
//
#include <hip/hip_runtime.h>
#include <math.h>
#include <type_traits>

#define N_NODES 50000
#define N_EDGES 800000
#define SCAN_BLK 2048   // elements per scan block (256 threads x 8)

using short8  = __attribute__((ext_vector_type(8))) short;
using floatx4 = __attribute__((ext_vector_type(4))) float;
using floatx2 = __attribute__((ext_vector_type(2))) float;
using ushortx4 = __attribute__((ext_vector_type(4))) unsigned short;
using uintx4  = __attribute__((ext_vector_type(4))) unsigned;
using uintx2  = __attribute__((ext_vector_type(2))) unsigned;

__device__ inline unsigned short f2bf(float f) {
  unsigned u = __float_as_uint(f);
  u += 0x7fff + ((u >> 16) & 1);   // round-to-nearest-even
  return (unsigned short)(u >> 16);
}

__device__ inline float sigmoidf(float x) { return 1.0f / (1.0f + __expf(-x)); }

// ---------------- CSR build ----------------

__global__ void count_kernel(const int* __restrict__ rows, int* __restrict__ counts, int E) {
  int e = blockIdx.x * 256 + threadIdx.x;
  if (e < E) atomicAdd(&counts[rows[e]], 1);
}

// pass1: per-block sums. N % 8 == 0 so (base < N) => full 8 in-bounds.
__global__ void scan_pass1(const int* __restrict__ counts, int* __restrict__ bsum, int N) {
  int base = blockIdx.x * SCAN_BLK + threadIdx.x * 8;
  int s = 0;
  if (base < N) {
#pragma unroll
    for (int j = 0; j < 8; ++j) s += counts[base + j];
  }
#pragma unroll
  for (int d = 32; d > 0; d >>= 1) s += __shfl_down(s, d, 64);
  __shared__ int wsum[4];
  int lane = threadIdx.x & 63, wv = threadIdx.x >> 6;
  if (lane == 0) wsum[wv] = s;
  __syncthreads();
  if (threadIdx.x == 0) bsum[blockIdx.x] = wsum[0] + wsum[1] + wsum[2] + wsum[3];
}

// pass3 (pass2 folded in): wave0 computes this block's global offset from bsum
// (<=64 entries) in-wave; block 0 also writes row_ptr[N] = total.
__global__ void scan_pass3(const int* __restrict__ counts, const int* __restrict__ bsum,
                           int* __restrict__ row_ptr, int* __restrict__ cursor, int N, int B) {
  __shared__ int blk_off_s, total_s;
  int tid = threadIdx.x, lane = tid & 63, wv = tid >> 6;
  if (wv == 0) {
    int b = (lane < B) ? bsum[lane] : 0;
    int pre = (lane < (int)blockIdx.x) ? b : 0;   // sum of bsum[0..blockIdx-1]
    int tot = b;
#pragma unroll
    for (int d = 32; d > 0; d >>= 1) { pre += __shfl_down(pre, d, 64); tot += __shfl_down(tot, d, 64); }
    if (lane == 0) { blk_off_s = pre; total_s = tot; }
  }
  __syncthreads();
  if (blockIdx.x == 0 && tid == 0) row_ptr[N] = total_s;
  int base = blockIdx.x * SCAN_BLK + tid * 8;
  int v[8];
  int s = 0;
  if (base < N) {
#pragma unroll
    for (int j = 0; j < 8; ++j) { v[j] = counts[base + j]; s += v[j]; }
  } else {
#pragma unroll
    for (int j = 0; j < 8; ++j) v[j] = 0;
  }
  int x = s;
#pragma unroll
  for (int d = 1; d < 64; d <<= 1) {
    int y = __shfl_up(x, d, 64);
    if (lane >= d) x += y;
  }
  __shared__ int wsum[4];
  if (lane == 63) wsum[wv] = x;
  __syncthreads();
  int woff = 0;
  for (int w = 0; w < wv; ++w) woff += wsum[w];
  int run = blk_off_s + woff + (x - s);   // exclusive offset of this thread's first elem
  if (base < N) {
#pragma unroll
    for (int j = 0; j < 8; ++j) {
      row_ptr[base + j] = run;
      cursor[base + j] = run;
      run += v[j];
    }
  }
}

__global__ void scatter_kernel(const int* __restrict__ rows, const int* __restrict__ cols,
                               const float* __restrict__ vals, int* __restrict__ cursor,
                               int* __restrict__ col_idx, float* __restrict__ val_srt, int E) {
  int e = blockIdx.x * 256 + threadIdx.x;
  if (e >= E) return;
  int r = rows[e];
  int p = atomicAdd(&cursor[r], 1);
  col_idx[p] = cols[e];
  val_srt[p] = vals[e];
}

// ---------------- fused cast (x -> bf16) + weight pack ----------------
// Blocks [0, castB): cast x (n4 float4 groups). Blocks [castB, castB+768): pack weights.
// W [K,M] row-major -> Wp[m*K+k] = bf16(W[k,m]).
__global__ void cast_pack_kernel(const float* __restrict__ x, unsigned short* __restrict__ xb, int n4,
                                 int castB,
                                 const float* __restrict__ W1, const float* __restrict__ G1,
                                 const float* __restrict__ W2, const float* __restrict__ G2,
                                 unsigned short* __restrict__ Wp1, unsigned short* __restrict__ Gp1,
                                 unsigned short* __restrict__ Wp2, unsigned short* __restrict__ Gp2) {
  if ((int)blockIdx.x < castB) {
    int i = blockIdx.x * 256 + threadIdx.x;
    if (i >= n4) return;
    floatx4 v = ((const floatx4*)x)[i];
    ushortx4 o;
    o[0] = f2bf(v[0]); o[1] = f2bf(v[1]); o[2] = f2bf(v[2]); o[3] = f2bf(v[3]);
    ((ushortx4*)xb)[i] = o;
  } else {
    int idx = (blockIdx.x - castB) * 256 + threadIdx.x;
    if (idx < 65536) {
      int m = idx >> 8, k = idx & 255;
      Wp1[idx] = f2bf(W1[k * 256 + m]);
    } else if (idx < 131072) {
      int t = idx - 65536; int m = t >> 8, k = t & 255;
      Gp1[t] = f2bf(G1[k * 256 + m]);
    } else if (idx < 163840) {
      int t = idx - 131072; int m = t >> 8, k = t & 255;
      Wp2[t] = f2bf(W2[k * 128 + m]);
    } else {
      int t = idx - 163840; int m = t >> 8, k = t & 255;
      Gp2[t] = f2bf(G2[k * 128 + m]);
    }
  }
}

// ---------------- fused dual GEMM: S = A@W, G = A@G, written interleaved bf16 ----------------
// Block = 64 rows x M cols; wave wid owns col-tiles [wid*WT, (wid+1)*WT) across ALL 64 rows.
// A frag: lane holds A[m=lane&15][k=quad*8+j]; C/D: D[row=quad*4+reg][col=lane&15] (m89/m91)
template <int MT_TOTAL>   // M = MT_TOTAL*16; WT = MT_TOTAL/4 col tiles per wave
__global__ __launch_bounds__(256) void gemm_dual_kernel(const unsigned short* __restrict__ A,
                                                        const unsigned short* __restrict__ Wp,
                                                        const unsigned short* __restrict__ Gp,
                                                        unsigned* __restrict__ SG, int N) {
  constexpr int K = 256;
  constexpr int M = MT_TOTAL * 16;
  constexpr int WT = MT_TOTAL / 4;
  int lane = threadIdx.x & 63;
  int wid = threadIdx.x >> 6;
  int r0 = blockIdx.x * 64;
  if (r0 >= N) return;
  int quad = lane >> 4, lr = lane & 15;
  int t0 = wid * WT;

  const short* Ab[4];
#pragma unroll
  for (int g = 0; g < 4; ++g) {
    int row = r0 + g * 16 + lr;
    if (row > N - 1) row = N - 1;   // clamp loads; stores guarded below
    Ab[g] = (const short*)A + (size_t)row * K + quad * 8;
  }
  const short* Wb[WT];
  const short* Gb[WT];
#pragma unroll
  for (int t = 0; t < WT; ++t) {
    size_t boff = (size_t)(t0 + t) * 16 * K + (size_t)lr * K + quad * 8;
    Wb[t] = (const short*)Wp + boff;
    Gb[t] = (const short*)Gp + boff;
  }

  floatx4 zero = {0.f, 0.f, 0.f, 0.f};
  floatx4 accS[4][WT], accG[4][WT];
#pragma unroll
  for (int g = 0; g < 4; ++g)
#pragma unroll
    for (int t = 0; t < WT; ++t) { accS[g][t] = zero; accG[g][t] = zero; }

  for (int kc = 0; kc < K / 32; ++kc) {
    short8 a[4];
#pragma unroll
    for (int g = 0; g < 4; ++g) a[g] = *(const short8*)(Ab[g] + kc * 32);
#pragma unroll
    for (int t = 0; t < WT; ++t) {
      short8 bw = *(const short8*)(Wb[t] + kc * 32);
      short8 bg = *(const short8*)(Gb[t] + kc * 32);
#pragma unroll
      for (int g = 0; g < 4; ++g) {
        accS[g][t] = __builtin_amdgcn_mfma_f32_16x16x32_bf16(a[g], bw, accS[g][t], 0, 0, 0);
        accG[g][t] = __builtin_amdgcn_mfma_f32_16x16x32_bf16(a[g], bg, accG[g][t], 0, 0, 0);
      }
    }
  }

#pragma unroll
  for (int g = 0; g < 4; ++g) {
    int orow = r0 + g * 16 + quad * 4;
#pragma unroll
    for (int t = 0; t < WT; ++t)
#pragma unroll
      for (int gg = 0; gg < 4; ++gg) {
        int row = orow + gg;
        if (row < N) {
          unsigned s = f2bf(accS[g][t][gg]);
          unsigned g2 = f2bf(accG[g][t][gg]);
          SG[(size_t)row * M + (t0 + t) * 16 + lr] = s | (g2 << 16);
        }
      }
  }
}

// ---------------- fused SpMM pair + gating (bf16 interleaved SG input) ----------------
// ROW PAIR per wave (avg degree 16 -> single-row waves drain too fast to hide latency):
// per iteration 4 edges from row A + 4 from row B = 8 independent 16B/8B gathers in
// flight; exhausted rows pad with v=0, clamped index (L1-hit). Gate read as asfloat(u):
// low-16 S bits perturb G mantissa <2^-8 rel (one extra bf16-grade rounding).
template <int D, bool WRITE_H>
__global__ __launch_bounds__(256) void spmm_gated_kernel(const int* __restrict__ row_ptr,
                                                         const int* __restrict__ col_idx,
                                                         const float* __restrict__ val,
                                                         const unsigned* __restrict__ SG,
                                                         unsigned short* __restrict__ hb,
                                                         float* __restrict__ out, int N, int E) {
  constexpr int PF = D / 64;   // uints (SG pairs) per lane: 4 for D=256, 2 for D=128
  using uvec = typename std::conditional<PF == 4, uintx4, uintx2>::type;
  int lane = threadIdx.x & 63;
  int wid = threadIdx.x >> 6;
  int pr = blockIdx.x * 4 + wid;   // pair index
  int rA = pr * 2;
  if (rA >= N) return;             // N even -> rA+1 < N whenever rA < N
  int eA = row_ptr[rA];
  int e1A = row_ptr[rA + 1];
  int e1B = row_ptr[rA + 2];
  int eB = e1A;

  float aS[2][PF], aG[2][PF];
#pragma unroll
  for (int h = 0; h < 2; ++h)
#pragma unroll
    for (int i = 0; i < PF; ++i) { aS[h][i] = 0.f; aG[h][i] = 0.f; }

  while (eA < e1A || eB < e1B) {
    unsigned c[8];
    float v[8];
#pragma unroll
    for (int i = 0; i < 4; ++i) {
      int ia = eA + i;
      int iac = (ia < E - 1) ? ia : E - 1;
      c[i] = (unsigned)col_idx[iac];
      v[i] = (ia < e1A) ? val[iac] : 0.f;
      int ib = eB + i;
      int ibc = (ib < E - 1) ? ib : E - 1;
      c[4 + i] = (unsigned)col_idx[ibc];
      v[4 + i] = (ib < e1B) ? val[ibc] : 0.f;
    }
    uvec p[8];
#pragma unroll
    for (int i = 0; i < 8; ++i)
      p[i] = ((const uvec*)(SG + (size_t)c[i] * D))[lane];
#pragma unroll
    for (int i = 0; i < 8; ++i) {
      int h = i >> 2;
#pragma unroll
      for (int q = 0; q < PF; ++q) {
        unsigned u = p[i][q];
        aS[h][q] += __uint_as_float(u << 16) * v[i];
        aG[h][q] += __uint_as_float(u) * v[i];   // G + <2^-8 rel mantissa noise
      }
    }
    eA += 4;
    eB += 4;
  }

#pragma unroll
  for (int h = 0; h < 2; ++h) {
    int r = rA + h;
    if constexpr (WRITE_H) {
      ushortx4 o;
#pragma unroll
      for (int i = 0; i < PF; ++i) {
        float hv = sigmoidf(aG[h][i]) * aS[h][i];
        o[i] = f2bf(hv > 0.f ? hv : 0.f);
      }
      ((ushortx4*)(hb + (size_t)r * 256))[lane] = o;   // only instantiated with D=256
    } else {
      if constexpr (PF == 4) {
        floatx4 o;
#pragma unroll
        for (int i = 0; i < 4; ++i) o[i] = sigmoidf(aG[h][i]) * aS[h][i];
        ((floatx4*)(out + (size_t)r * D))[lane] = o;
      } else {
        floatx2 o;
#pragma unroll
        for (int i = 0; i < 2; ++i) o[i] = sigmoidf(aG[h][i]) * aS[h][i];
        ((floatx2*)(out + (size_t)r * D))[lane] = o;
      }
    }
  }
}

// ---------------- launch ----------------

extern "C" void kernel_launch(void* const* d_in, const int* in_sizes, int n_in,
                              void* d_out, int out_size, void* d_ws, size_t ws_size,
                              hipStream_t stream) {
  const float* x    = (const float*)d_in[0];
  const int*   rows = (const int*)d_in[1];
  const int*   cols = (const int*)d_in[2];
  const float* vals = (const float*)d_in[3];
  const float* W1   = (const float*)d_in[4];
  const float* G1   = (const float*)d_in[5];
  const float* W2   = (const float*)d_in[6];
  const float* G2   = (const float*)d_in[7];

  const int N = N_NODES, E = N_EDGES;
  char* ws = (char*)d_ws;
  size_t off = 0;
  auto alloc = [&](size_t bytes) -> char* {
    off = (off + 255) & ~(size_t)255;
    char* p = ws + off;
    off += bytes;
    return p;
  };
  int*   counts  = (int*)alloc((size_t)N * 4);
  int*   row_ptr = (int*)alloc((size_t)(N + 1) * 4);
  int*   cursor  = (int*)alloc((size_t)N * 4);
  int*   bsum    = (int*)alloc(64 * 4);
  int*   col_idx = (int*)alloc((size_t)E * 4);
  float* val_srt = (float*)alloc((size_t)E * 4);
  unsigned short* xb  = (unsigned short*)alloc((size_t)N * 256 * 2);
  unsigned short* hb  = (unsigned short*)alloc((size_t)N * 256 * 2);
  unsigned short* Wp1 = (unsigned short*)alloc(256 * 256 * 2);
  unsigned short* Gp1 = (unsigned short*)alloc(256 * 256 * 2);
  unsigned short* Wp2 = (unsigned short*)alloc(256 * 128 * 2);
  unsigned short* Gp2 = (unsigned short*)alloc(256 * 128 * 2);
  unsigned* SG1 = (unsigned*)alloc((size_t)N * 256 * 4);   // [N][256] uints = {S,G} bf16 pairs
  unsigned* SG2 = (unsigned*)alloc((size_t)N * 128 * 4);   // [N][128] uints

  // CSR build (per launch; same work every call)
  (void)hipMemsetAsync(counts, 0, (size_t)N * 4, stream);
  count_kernel<<<(E + 255) / 256, 256, 0, stream>>>(rows, counts, E);
  int scanB = (N + SCAN_BLK - 1) / SCAN_BLK;   // 25
  scan_pass1<<<scanB, 256, 0, stream>>>(counts, bsum, N);
  scan_pass3<<<scanB, 256, 0, stream>>>(counts, bsum, row_ptr, cursor, N, scanB);
  scatter_kernel<<<(E + 255) / 256, 256, 0, stream>>>(rows, cols, vals, cursor, col_idx, val_srt, E);

  // fused cast + pack
  int n4 = N * 256 / 4;
  int castB = (n4 + 255) / 256;
  cast_pack_kernel<<<castB + 768, 256, 0, stream>>>(x, xb, n4, castB,
                                                    W1, G1, W2, G2, Wp1, Gp1, Wp2, Gp2);

  int gemm_blocks = (N + 63) / 64;
  int spmm_blocks = (N / 2 + 3) / 4;

  // layer 1
  gemm_dual_kernel<16><<<gemm_blocks, 256, 0, stream>>>(xb, Wp1, Gp1, SG1, N);
  spmm_gated_kernel<256, true><<<spmm_blocks, 256, 0, stream>>>(row_ptr, col_idx, val_srt,
                                                                SG1, hb, nullptr, N, E);
  // layer 2
  gemm_dual_kernel<8><<<gemm_blocks, 256, 0, stream>>>(hb, Wp2, Gp2, SG2, N);
  spmm_gated_kernel<128, false><<<spmm_blocks, 256, 0, stream>>>(row_ptr, col_idx, val_srt,
                                                                 SG2, nullptr, (float*)d_out, N, E);
}